// Round 1
// baseline (236.789 us; speedup 1.0000x reference)
//
#include <hip/hip_runtime.h>
#include <cstdint>

#define NROWS 131072
#define HD    128      // H == IN == 128
#define NDIM  512      // 4*H
#define OUTQ  16777216 // NROWS*HD

using bf16x8 = __attribute__((ext_vector_type(8))) short;
using f32x4  = __attribute__((ext_vector_type(4))) float;

__device__ __forceinline__ uint32_t bf16rne(float f) {
  uint32_t u = __builtin_bit_cast(uint32_t, f);
  return (u + 0x7fffu + ((u >> 16) & 1u)) >> 16;
}

__device__ __forceinline__ float tanhf_fast(float v) {
  float a = __builtin_fabsf(v);
  float e = __expf(-2.0f * a);
  float t = (1.0f - e) * __builtin_amdgcn_rcpf(1.0f + e);
  return v < 0.0f ? -t : t;
}

// Pack Wf[k][n] = W[k][n] + (k>=128 ? r[k-128][n] : 0) as bf16 in MFMA
// B-fragment order: frag index (ntile*8 + kstep)*64 + lane, 8 bf16 each,
// element j -> Wf[kstep*32 + (lane>>4)*8 + j][ntile*16 + (lane&15)].
__global__ __launch_bounds__(256) void pack_weights(
    const float* __restrict__ W, const float* __restrict__ r,
    uint16_t* __restrict__ Bp) {
  int idx = blockIdx.x * 256 + threadIdx.x;   // 16384 frags total
  int l  = idx & 63;
  int ts = idx >> 6;
  int s  = ts & 7;
  int t  = ts >> 3;
  int ncol  = t * 16 + (l & 15);
  int kbase = s * 32 + ((l >> 4) << 3);
  uint32_t w[4];
#pragma unroll
  for (int jj = 0; jj < 4; ++jj) {
    int k0 = kbase + 2 * jj;
    float v0 = W[k0 * NDIM + ncol];
    float v1 = W[(k0 + 1) * NDIM + ncol];
    if (k0 >= 128)     v0 += r[(k0 - 128) * NDIM + ncol];
    if (k0 + 1 >= 128) v1 += r[(k0 + 1 - 128) * NDIM + ncol];
    w[jj] = bf16rne(v0) | (bf16rne(v1) << 16);
  }
  reinterpret_cast<uint4*>(Bp)[idx] = make_uint4(w[0], w[1], w[2], w[3]);
}

__global__ __launch_bounds__(256, 3) void slstm_fused(
    const float* __restrict__ x,  const float* __restrict__ h,
    const float* __restrict__ cs, const float* __restrict__ ns,
    const float* __restrict__ ms, const float* __restrict__ bias,
    const uint16_t* __restrict__ Bp, float* __restrict__ out) {
  // LDS: 64 rows x 256 bf16 (x|h concatenated), XOR-swizzled to avoid
  // 16-way bank conflicts on ds_read_b128 fragment reads.
  __shared__ __align__(16) char smem[64 * 512];
  const int tid  = threadIdx.x;
  const int wave = tid >> 6;
  const int lane = tid & 63;
  const int row0 = blockIdx.x * 64;

  // ---- stage x (cols 0..127) ----
#pragma unroll
  for (int i = 0; i < 8; ++i) {
    int e   = (i * 256 + tid) * 4;   // element in 64x128 block
    int rw  = e >> 7;
    int col = e & 127;
    float4 v = *reinterpret_cast<const float4*>(x + (size_t)(row0 + rw) * HD + col);
    uint32_t lo = bf16rne(v.x) | (bf16rne(v.y) << 16);
    uint32_t hi = bf16rne(v.z) | (bf16rne(v.w) << 16);
    int off = (rw * 512 + col * 2) ^ ((rw & 7) << 4);
    *reinterpret_cast<uint2*>(smem + off) = make_uint2(lo, hi);
  }
  // ---- stage h (cols 128..255) ----
#pragma unroll
  for (int i = 0; i < 8; ++i) {
    int e   = (i * 256 + tid) * 4;
    int rw  = e >> 7;
    int col = e & 127;
    float4 v = *reinterpret_cast<const float4*>(h + (size_t)(row0 + rw) * HD + col);
    uint32_t lo = bf16rne(v.x) | (bf16rne(v.y) << 16);
    uint32_t hi = bf16rne(v.z) | (bf16rne(v.w) << 16);
    int off = (rw * 512 + 256 + col * 2) ^ ((rw & 7) << 4);
    *reinterpret_cast<uint2*>(smem + off) = make_uint2(lo, hi);
  }
  __syncthreads();

  // ---- load this wave's 8 A k-fragments (16 rows) into registers ----
  bf16x8 a[8];
  {
    int rw   = wave * 16 + (lane & 15);
    int base = rw * 512 + ((lane >> 4) << 4);
    int swz  = (rw & 7) << 4;
#pragma unroll
    for (int s = 0; s < 8; ++s)
      a[s] = *reinterpret_cast<const bf16x8*>(smem + ((base + s * 64) ^ swz));
  }

  const bf16x8* __restrict__ Bf = reinterpret_cast<const bf16x8*>(Bp);
  const int l15  = lane & 15;
  const int rowb = row0 + wave * 16 + ((lane >> 4) << 2);

  // ---- 8 column groups; each: 4 gate-tiles x 8 k-steps of MFMA, then
  //      lane-local epilogue (i,f,z,o for col j all live in this lane) ----
  for (int t = 0; t < 8; ++t) {
    f32x4 acc0 = {0.f, 0.f, 0.f, 0.f};
    f32x4 acc1 = {0.f, 0.f, 0.f, 0.f};
    f32x4 acc2 = {0.f, 0.f, 0.f, 0.f};
    f32x4 acc3 = {0.f, 0.f, 0.f, 0.f};
#pragma unroll
    for (int s = 0; s < 8; ++s) {
      acc0 = __builtin_amdgcn_mfma_f32_16x16x32_bf16(a[s], Bf[((t     ) * 8 + s) * 64 + lane], acc0, 0, 0, 0);
      acc1 = __builtin_amdgcn_mfma_f32_16x16x32_bf16(a[s], Bf[((t +  8) * 8 + s) * 64 + lane], acc1, 0, 0, 0);
      acc2 = __builtin_amdgcn_mfma_f32_16x16x32_bf16(a[s], Bf[((t + 16) * 8 + s) * 64 + lane], acc2, 0, 0, 0);
      acc3 = __builtin_amdgcn_mfma_f32_16x16x32_bf16(a[s], Bf[((t + 24) * 8 + s) * 64 + lane], acc3, 0, 0, 0);
    }
    int j = t * 16 + l15;
    float bi  = bias[j];
    float bf_ = bias[128 + j];
    float bz  = bias[256 + j];
    float bo  = bias[384 + j];
#pragma unroll
    for (int rg = 0; rg < 4; ++rg) {
      int row = rowb + rg;
      int p   = row * HD + j;
      float i_raw = acc0[rg] + bi;
      float f_raw = acc1[rg] + bf_;
      float z_raw = acc2[rg] + bz;
      float o_raw = acc3[rg] + bo;
      float cv = cs[p], nv = ns[p], mv = ms[p];
      float ef  = __expf(-f_raw);
      float den = 1.0f + ef;
      float fg  = __builtin_amdgcn_rcpf(den);   // sigmoid(f_raw)
      float lgf = -__logf(den);                 // log sigmoid(f_raw)
      float mn  = fmaxf(lgf + mv, i_raw);       // m_new
      float ip  = __expf(i_raw - mn);           // i'
      float zt  = tanhf_fast(z_raw);
      float og  = __builtin_amdgcn_rcpf(1.0f + __expf(-o_raw));
      float cn_ = fg * cv + ip * zt;            // c_new (f' == f per source)
      float nn_ = fg * nv + ip;                 // n_new
      float hn  = og * tanhf_fast(cn_ * __builtin_amdgcn_rcpf(nn_));
      out[p]            = hn;
      out[p + OUTQ]     = cn_;
      out[p + 2 * OUTQ] = nn_;
      out[p + 3 * OUTQ] = mn;
    }
  }
}

extern "C" void kernel_launch(void* const* d_in, const int* in_sizes, int n_in,
                              void* d_out, int out_size, void* d_ws, size_t ws_size,
                              hipStream_t stream) {
  const float* x = (const float*)d_in[0];
  const float* h = (const float*)d_in[1];
  const float* c = (const float*)d_in[2];
  const float* n = (const float*)d_in[3];
  const float* m = (const float*)d_in[4];
  const float* W = (const float*)d_in[5];
  const float* r = (const float*)d_in[6];
  const float* b = (const float*)d_in[7];
  uint16_t* Bp = (uint16_t*)d_ws;   // 256 KB packed bf16 weights

  pack_weights<<<64, 256, 0, stream>>>(W, r, Bp);
  slstm_fused<<<NROWS / 64, 256, 0, stream>>>(x, h, c, n, m, b, Bp, (float*)d_out);
}